// Round 4
// baseline (2196.445 us; speedup 1.0000x reference)
//
#include <hip/hip_runtime.h>
#include <hip/hip_bf16.h>
#include <cstdint>
#include <cstddef>

// ---------------------------------------------------------------------------
// SceneRFHead forward on MI355X.
// Pipeline: bev transpose (-> channel-contiguous voxel grid, fp32 if ws fits,
//           else fp16) -> ray setup -> gaussian MLP -> per-ray sample
//           build+sort -> main MLP -> volume render + losses -> total.
// MLP math fp32 (VALU). Round-2 lesson: bf16 voxel features gave depth
// absmax 0.56 > 0.24 threshold (error amplified through 11 layers into
// sigma -> depth). Features must be >= fp16 precision; fp32 preferred.
// (Round 3 was a broker timeout; this source is the round-2 kernel, unchanged.)
// ---------------------------------------------------------------------------

namespace {

constexpr int R_RAYS = 4096;
constexpr int IMG_H_ = 900, IMG_W_ = 1600;
constexpr int NVOX   = 8 * 200 * 200;   // 320000 voxels, 128 channels each

__device__ __forceinline__ float h2f(uint16_t b){ _Float16 h; __builtin_memcpy(&h, &b, 2); return (float)h; }
__device__ __forceinline__ uint16_t f2h(float f){ _Float16 h = (_Float16)f; uint16_t b; __builtin_memcpy(&b, &h, 2); return b; }

// ---------------- bev (1024,200,200) -> vox[(z*200+x)*200+y][c] -------------
template<typename VT>
__global__ __launch_bounds__(256) void k_transpose(const float* __restrict__ bev,
                                                   VT* __restrict__ vox){
  int v = blockIdx.x * 256 + threadIdx.x;
  if (v >= NVOX) return;
  // v = z*40000 + x*200 + y ; reshaped (c,z,x,y): bev[c*320000 + v]
  #pragma unroll 1
  for (int c0 = 0; c0 < 128; c0 += 8){
    float f[8];
    #pragma unroll
    for (int j = 0; j < 8; ++j) f[j] = bev[(size_t)(c0 + j) * NVOX + v];
    if constexpr (sizeof(VT) == 4){
      float4 v0, v1;
      v0.x=f[0]; v0.y=f[1]; v0.z=f[2]; v0.w=f[3];
      v1.x=f[4]; v1.y=f[5]; v1.z=f[6]; v1.w=f[7];
      float* dst = (float*)(vox + (size_t)v * 128 + c0);
      reinterpret_cast<float4*>(dst)[0] = v0;
      reinterpret_cast<float4*>(dst)[1] = v1;
    } else {
      uint4 pk;
      pk.x = (uint32_t)f2h(f[0]) | ((uint32_t)f2h(f[1]) << 16);
      pk.y = (uint32_t)f2h(f[2]) | ((uint32_t)f2h(f[3]) << 16);
      pk.z = (uint32_t)f2h(f[4]) | ((uint32_t)f2h(f[5]) << 16);
      pk.w = (uint32_t)f2h(f[6]) | ((uint32_t)f2h(f[7]) << 16);
      *reinterpret_cast<uint4*>((uint16_t*)vox + (size_t)v * 128 + c0) = pk;
    }
  }
}

// load 16 consecutive channels as float
template<typename VT>
__device__ __forceinline__ void load16(const VT* __restrict__ base, float f[16]){
  if constexpr (sizeof(VT) == 4){
    const float4* sp = reinterpret_cast<const float4*>((const float*)base);
    float4 a = sp[0], b = sp[1], c = sp[2], d = sp[3];
    f[0]=a.x; f[1]=a.y; f[2]=a.z; f[3]=a.w;
    f[4]=b.x; f[5]=b.y; f[6]=b.z; f[7]=b.w;
    f[8]=c.x; f[9]=c.y; f[10]=c.z; f[11]=c.w;
    f[12]=d.x; f[13]=d.y; f[14]=d.z; f[15]=d.w;
  } else {
    const uint4* sp = reinterpret_cast<const uint4*>((const uint16_t*)base);
    uint4 u0 = sp[0], u1 = sp[1];
    uint32_t uu[8] = {u0.x,u0.y,u0.z,u0.w,u1.x,u1.y,u1.z,u1.w};
    #pragma unroll
    for (int q = 0; q < 8; ++q){
      f[2*q]   = h2f((uint16_t)(uu[q] & 0xffffu));
      f[2*q+1] = h2f((uint16_t)(uu[q] >> 16));
    }
  }
}

// ---------------- bilinear image sample (matches _sample_img clipping) ------
__device__ __forceinline__ void sample_img3(const float* __restrict__ img, float u, float v,
                                            float out3[3]){
  float x0f = fminf(fmaxf(floorf(u), 0.f), (float)(IMG_W_ - 2));
  float y0f = fminf(fmaxf(floorf(v), 0.f), (float)(IMG_H_ - 2));
  int x0 = (int)x0f, y0 = (int)y0f;
  float fx = fminf(fmaxf(u - x0f, 0.f), 1.f);
  float fy = fminf(fmaxf(v - y0f, 0.f), 1.f);
  float w00 = (1.f-fx)*(1.f-fy), w01 = fx*(1.f-fy), w10 = (1.f-fx)*fy, w11 = fx*fy;
  #pragma unroll
  for (int c = 0; c < 3; ++c){
    const float* pl = img + (size_t)c * IMG_H_ * IMG_W_ + (size_t)y0 * IMG_W_ + x0;
    out3[c] = pl[0]*w00 + pl[1]*w01 + pl[IMG_W_]*w10 + pl[IMG_W_+1]*w11;
  }
}

// ---------------- per-ray setup --------------------------------------------
__global__ __launch_bounds__(256) void k_raysetup(const float* __restrict__ pix,
                                                  const float* __restrict__ camK,
                                                  const float* __restrict__ s2i,
                                                  const float* __restrict__ src,
                                                  float* __restrict__ ray_dir,
                                                  float* __restrict__ ray_vd,
                                                  float* __restrict__ cam_dir,
                                                  float* __restrict__ src_col){
  int r = blockIdx.x * 256 + threadIdx.x;
  if (r >= R_RAYS) return;
  // inverse of 3x3 cam_K (adjugate / det)
  float a=camK[0],b=camK[1],c=camK[2],d=camK[3],e=camK[4],f=camK[5],g=camK[6],h=camK[7],i=camK[8];
  float A = (e*i - f*h), B = -(d*i - f*g), C = (d*h - e*g);
  float det = a*A + b*B + c*C;
  float id = 1.f / det;
  float inv[9];
  inv[0] = A*id;            inv[1] = (c*h - b*i)*id;  inv[2] = (b*f - c*e)*id;
  inv[3] = B*id;            inv[4] = (a*i - c*g)*id;  inv[5] = (c*d - a*f)*id;
  inv[6] = C*id;            inv[7] = (b*g - a*h)*id;  inv[8] = (a*e - b*d)*id;
  float u = pix[2*r], v = pix[2*r+1];
  // cam_dirs = pix_h @ invK.T
  float cd0 = inv[0]*u + inv[1]*v + inv[2];
  float cd1 = inv[3]*u + inv[4]*v + inv[5];
  float cd2 = inv[6]*u + inv[7]*v + inv[8];
  // dirs_lidar = cam_dirs @ Rm.T
  float dl0 = s2i[0]*cd0 + s2i[1]*cd1 + s2i[2]*cd2;
  float dl1 = s2i[4]*cd0 + s2i[5]*cd1 + s2i[6]*cd2;
  float dl2 = s2i[8]*cd0 + s2i[9]*cd1 + s2i[10]*cd2;
  float nrm = sqrtf(dl0*dl0 + dl1*dl1 + dl2*dl2);
  float inn = 1.f / nrm;
  ray_dir[3*r] = dl0;  ray_dir[3*r+1] = dl1;  ray_dir[3*r+2] = dl2;
  ray_vd[3*r] = dl0*inn; ray_vd[3*r+1] = dl1*inn; ray_vd[3*r+2] = dl2*inn;
  cam_dir[3*r] = cd0;  cam_dir[3*r+1] = cd1;  cam_dir[3*r+2] = cd2;
  float sc[3]; sample_img3(src, u, v, sc);
  src_col[3*r] = sc[0]; src_col[3*r+1] = sc[1]; src_col[3*r+2] = sc[2];
}

// ---------------- fp32 4x4 register-tile micro-GEMM on LDS activations ------
template<int ACOLS, int KTOT, int KROWS>
__device__ __forceinline__ void gemm_f32(const float* __restrict__ A, const float* __restrict__ W,
                                         int p0, int j0, float acc[4][4]){
  #pragma unroll 2
  for (int k = 0; k < KTOT; k += 4){
    float a_[4][4];
    #pragma unroll
    for (int i = 0; i < 4; ++i){
      float4 t = *reinterpret_cast<const float4*>(A + (p0+i)*ACOLS + k);
      a_[i][0]=t.x; a_[i][1]=t.y; a_[i][2]=t.z; a_[i][3]=t.w;
    }
    float w_[4][4];
    #pragma unroll
    for (int kk = 0; kk < 4; ++kk){
      float4 t;
      if constexpr (KROWS < KTOT){
        if (k + kk < KROWS) t = *reinterpret_cast<const float4*>(W + (size_t)(k+kk)*128 + j0);
        else { t.x = t.y = t.z = t.w = 0.f; }
      } else {
        t = *reinterpret_cast<const float4*>(W + (size_t)(k+kk)*128 + j0);
      }
      w_[kk][0]=t.x; w_[kk][1]=t.y; w_[kk][2]=t.z; w_[kk][3]=t.w;
    }
    #pragma unroll
    for (int i = 0; i < 4; ++i)
      #pragma unroll
      for (int kk = 0; kk < 4; ++kk)
        #pragma unroll
        for (int jj = 0; jj < 4; ++jj)
          acc[i][jj] = fmaf(a_[i][kk], w_[kk][jj], acc[i][jj]);
  }
}

// ---------------- fused trilinear + posenc + ResNet MLP ---------------------
// 32 points per 256-thread block. MODE 0: gaussian centers; MODE 1: d_all samples.
template<int DOUT, int MODE, typename VT>
__global__ __launch_bounds__(256, 2) void k_mlp(
    const VT* __restrict__ vox,
    const float* __restrict__ ray_dir, const float* __restrict__ ray_vd,
    const float* __restrict__ s2i, const float* __restrict__ d_all,
    const float* __restrict__ Win, const float* __restrict__ bin,
    const float* __restrict__ Wz,  const float* __restrict__ bz,
    const float* __restrict__ W0,  const float* __restrict__ b0,
    const float* __restrict__ W1,  const float* __restrict__ b1,
    const float* __restrict__ Wout,const float* __restrict__ bout,
    float* __restrict__ outp)
{
  __shared__ float Hs[32*128];
  __shared__ float Ba[32*128];
  __shared__ float Bb[32*128];
  __shared__ float Zs[32*128];
  __shared__ float Xs[32*48];
  const int tid = threadIdx.x;

  // ---- prologue: trilinear features + positional encoding ----
  {
    const int p = tid >> 3, sub = tid & 7;
    const int idx = blockIdx.x * 32 + p;
    int r; float dval;
    if constexpr (MODE == 0){ r = idx >> 2; dval = 25.0f * ((float)(idx & 3) + 0.5f); }
    else                    { r = idx >> 6; dval = d_all[idx]; }
    const float ox = s2i[3], oy = s2i[7], oz = s2i[11];
    const float dx = ray_dir[3*r], dy = ray_dir[3*r+1], dz = ray_dir[3*r+2];
    const float px = ox + dx*dval, py = oy + dy*dval, pz = oz + dz*dval;
    const float gx = (px + 51.2f) * (199.0f/102.4f);
    const float gy = (py + 51.2f) * (199.0f/102.4f);
    const float gz = (pz + 5.0f)  * (7.0f/8.0f);
    const float valid = (gx>=0.f && gx<=199.f && gy>=0.f && gy<=199.f && gz>=0.f && gz<=7.f) ? 1.f : 0.f;
    float x0f = fminf(fmaxf(floorf(gx), 0.f), 198.f);
    float y0f = fminf(fmaxf(floorf(gy), 0.f), 198.f);
    float z0f = fminf(fmaxf(floorf(gz), 0.f), 6.f);
    int x0 = (int)x0f, y0 = (int)y0f, z0 = (int)z0f;
    float fx = fminf(fmaxf(gx - x0f, 0.f), 1.f);
    float fy = fminf(fmaxf(gy - y0f, 0.f), 1.f);
    float fz = fminf(fmaxf(gz - z0f, 0.f), 1.f);
    float wxv[2] = {1.f-fx, fx}, wyv[2] = {1.f-fy, fy}, wzv[2] = {(1.f-fz)*valid, fz*valid};
    const int c0 = sub * 16;
    float f[16];
    #pragma unroll
    for (int i2 = 0; i2 < 16; ++i2) f[i2] = 0.f;
    #pragma unroll
    for (int dzi = 0; dzi < 2; ++dzi)
      #pragma unroll
      for (int dxi = 0; dxi < 2; ++dxi)
        #pragma unroll
        for (int dyi = 0; dyi < 2; ++dyi){
          float wgt = wzv[dzi] * wxv[dxi] * wyv[dyi];
          size_t vi = ((size_t)(z0+dzi)*200 + (size_t)(x0+dxi))*200 + (size_t)(y0+dyi);
          float cf[16];
          load16<VT>(vox + vi*128 + c0, cf);
          #pragma unroll
          for (int q = 0; q < 16; ++q) f[q] = fmaf(wgt, cf[q], f[q]);
        }
    #pragma unroll
    for (int i2 = 0; i2 < 16; ++i2) Zs[p*128 + c0 + i2] = f[i2];
    if (sub < 6){
      const float fr = 3.14159265358979323846f * (float)(1 << sub);
      Xs[p*48 + 3 + 6*sub + 0] = sinf(px*fr);
      Xs[p*48 + 3 + 6*sub + 1] = sinf(py*fr);
      Xs[p*48 + 3 + 6*sub + 2] = sinf(pz*fr);
      Xs[p*48 + 3 + 6*sub + 3] = cosf(px*fr);
      Xs[p*48 + 3 + 6*sub + 4] = cosf(py*fr);
      Xs[p*48 + 3 + 6*sub + 5] = cosf(pz*fr);
    } else if (sub == 6){
      Xs[p*48+0] = px; Xs[p*48+1] = py; Xs[p*48+2] = pz;
      Xs[p*48+39] = ray_vd[3*r]; Xs[p*48+40] = ray_vd[3*r+1]; Xs[p*48+41] = ray_vd[3*r+2];
      Xs[p*48+42] = 0.f; Xs[p*48+43] = 0.f; Xs[p*48+44] = 0.f;
      Xs[p*48+45] = 0.f; Xs[p*48+46] = 0.f; Xs[p*48+47] = 0.f;
    }
  }
  __syncthreads();

  const int jg = tid & 31, pq = tid >> 5;
  const int p0 = pq * 4, j0 = jg * 4;
  float acc[4][4];

  // ---- input layer: H = Xin @ Win + bin ----
  #pragma unroll
  for (int i=0;i<4;++i) for (int j=0;j<4;++j) acc[i][j]=0.f;
  gemm_f32<48,44,42>(Xs, Win, p0, j0, acc);
  {
    float4 bv = *reinterpret_cast<const float4*>(bin + j0);
    #pragma unroll
    for (int i=0;i<4;++i){
      float4 hv; hv.x=acc[i][0]+bv.x; hv.y=acc[i][1]+bv.y; hv.z=acc[i][2]+bv.z; hv.w=acc[i][3]+bv.w;
      *reinterpret_cast<float4*>(Hs + (p0+i)*128 + j0) = hv;
    }
  }
  __syncthreads();

  #pragma unroll 1
  for (int blk = 0; blk < 3; ++blk){
    const float* Wzi = Wz + blk*16384;  const float* bzi = bz + blk*128;
    const float* W0i = W0 + blk*16384;  const float* b0i = b0 + blk*128;
    const float* W1i = W1 + blk*16384;  const float* b1i = b1 + blk*128;

    // a: H += Z @ Wz + bz ; Ba = relu(H)
    #pragma unroll
    for (int i=0;i<4;++i) for (int j=0;j<4;++j) acc[i][j]=0.f;
    gemm_f32<128,128,128>(Zs, Wzi, p0, j0, acc);
    {
      float4 bv = *reinterpret_cast<const float4*>(bzi + j0);
      #pragma unroll
      for (int i=0;i<4;++i){
        float* hp = Hs + (p0+i)*128 + j0;
        float4 h = *reinterpret_cast<float4*>(hp);
        h.x += acc[i][0]+bv.x; h.y += acc[i][1]+bv.y; h.z += acc[i][2]+bv.z; h.w += acc[i][3]+bv.w;
        *reinterpret_cast<float4*>(hp) = h;
        float4 rv; rv.x=fmaxf(h.x,0.f); rv.y=fmaxf(h.y,0.f); rv.z=fmaxf(h.z,0.f); rv.w=fmaxf(h.w,0.f);
        *reinterpret_cast<float4*>(Ba + (p0+i)*128 + j0) = rv;
      }
    }
    __syncthreads();

    // b: Bb = relu(Ba @ W0 + b0)
    #pragma unroll
    for (int i=0;i<4;++i) for (int j=0;j<4;++j) acc[i][j]=0.f;
    gemm_f32<128,128,128>(Ba, W0i, p0, j0, acc);
    {
      float4 bv = *reinterpret_cast<const float4*>(b0i + j0);
      #pragma unroll
      for (int i=0;i<4;++i){
        float4 rv;
        rv.x=fmaxf(acc[i][0]+bv.x,0.f); rv.y=fmaxf(acc[i][1]+bv.y,0.f);
        rv.z=fmaxf(acc[i][2]+bv.z,0.f); rv.w=fmaxf(acc[i][3]+bv.w,0.f);
        *reinterpret_cast<float4*>(Bb + (p0+i)*128 + j0) = rv;
      }
    }
    __syncthreads();

    // c: H += Bb @ W1 + b1
    #pragma unroll
    for (int i=0;i<4;++i) for (int j=0;j<4;++j) acc[i][j]=0.f;
    gemm_f32<128,128,128>(Bb, W1i, p0, j0, acc);
    {
      float4 bv = *reinterpret_cast<const float4*>(b1i + j0);
      #pragma unroll
      for (int i=0;i<4;++i){
        float* hp = Hs + (p0+i)*128 + j0;
        float4 h = *reinterpret_cast<float4*>(hp);
        h.x += acc[i][0]+bv.x; h.y += acc[i][1]+bv.y; h.z += acc[i][2]+bv.z; h.w += acc[i][3]+bv.w;
        *reinterpret_cast<float4*>(hp) = h;
      }
    }
    __syncthreads();
  }

  // ---- output layer: out = relu(H) @ Wout + bout ----
  {
    const int pp = tid >> 3, dd = tid & 7;
    if (dd < DOUT){
      float a = bout[dd];
      #pragma unroll 4
      for (int k = 0; k < 128; ++k)
        a = fmaf(fmaxf(Hs[pp*128 + k], 0.f), Wout[k*DOUT + dd], a);
      outp[(size_t)(blockIdx.x*32 + pp)*DOUT + dd] = a;
    }
  }
}

// ---------------- build sorted per-ray sample depths ------------------------
__global__ __launch_bounds__(256) void k_dall(const float* __restrict__ og,
                                              float* __restrict__ d_all,
                                              float* __restrict__ g_means,
                                              float* __restrict__ g_stds){
  int ray = blockIdx.x * 4 + (threadIdx.x >> 6);
  int lane = threadIdx.x & 63;
  float means[4], stds[4];
  #pragma unroll
  for (int g = 0; g < 4; ++g){
    float m0 = og[(ray*4 + g)*2 + 0], m1 = og[(ray*4 + g)*2 + 1];
    means[g] = (12.5f + 25.f*g) + tanhf(m0) * 12.5f;
    stds[g]  = 5.0f / (1.0f + expf(-m1)) + 0.001f;
  }
  float v;
  if (lane < 32) v = 0.5f + (float)lane * (99.5f/31.f);
  else {
    int g = (lane - 32) >> 3, li = (lane - 32) & 7;
    v = means[g] + (-1.f + (2.f/7.f)*(float)li) * (2.f * stds[g]);
  }
  v = fminf(fmaxf(v, 0.01f), 100.f);
  // bitonic sort across 64 lanes (ascending)
  #pragma unroll
  for (int k = 2; k <= 64; k <<= 1)
    #pragma unroll
    for (int j = k >> 1; j > 0; j >>= 1){
      float o = __shfl_xor(v, j);
      bool up  = ((lane & k) == 0);
      bool low = ((lane & j) == 0);
      float mn = fminf(v, o), mx = fmaxf(v, o);
      v = (up == low) ? mn : mx;
    }
  d_all[ray*64 + lane] = v;
  if (lane < 4){ g_means[ray*4 + lane] = means[lane]; g_stds[ray*4 + lane] = stds[lane]; }
}

__device__ __forceinline__ float wredsum(float x){
  #pragma unroll
  for (int off = 32; off > 0; off >>= 1) x += __shfl_xor(x, off);
  return x;
}

// ---------------- volume rendering + all losses -----------------------------
__global__ __launch_bounds__(256) void k_render(const float* __restrict__ outm,
                                                const float* __restrict__ d_all,
                                                const float* __restrict__ g_means,
                                                const float* __restrict__ g_stds,
                                                const float* __restrict__ src_col,
                                                const float* __restrict__ cam_dir,
                                                const float* __restrict__ s2t,
                                                const float* __restrict__ camK,
                                                const float* __restrict__ tgt_img,
                                                float* __restrict__ acc,
                                                float* __restrict__ out){
  int ray = blockIdx.x * 4 + (threadIdx.x >> 6);
  int lane = threadIdx.x & 63;
  float4 o = *reinterpret_cast<const float4*>(outm + (size_t)(ray*64 + lane)*4);
  float d = d_all[ray*64 + lane];
  float dn = __shfl_down(d, 1);
  float delta = (lane == 63) ? 1e10f : (dn - d);
  float sigma = fmaxf(o.x, 0.f);
  float alpha = 1.f - expf(-sigma * delta);
  float am = 1.f - alpha + 1e-10f;
  float P = am;
  #pragma unroll
  for (int off = 1; off < 64; off <<= 1){
    float t = __shfl_up(P, off);
    if (lane >= off) P *= t;
  }
  float T = __shfl_up(P, 1); if (lane == 0) T = 1.f;
  float w = alpha * T;
  float r0 = 1.f/(1.f+expf(-o.y));
  float r1 = 1.f/(1.f+expf(-o.z));
  float r2 = 1.f/(1.f+expf(-o.w));
  float depth = wredsum(w * d);
  float Sw    = wredsum(w);
  float c0 = wredsum(w*r0), c1 = wredsum(w*r1), c2 = wredsum(w*r2);
  float mg[4], sg[4];
  #pragma unroll
  for (int g = 0; g < 4; ++g){ mg[g] = g_means[ray*4+g]; sg[g] = g_stds[ray*4+g]; }
  float q = 0.f;
  #pragma unroll
  for (int g = 0; g < 4; ++g){ float t = (d - mg[g]) / sg[g]; q += expf(-0.5f*t*t) / sg[g]; }
  q *= 0.25f;
  float Sq = wredsum(q);
  float pw = w / (Sw + 1e-6f), qn = q / (Sq + 1e-6f);
  float kle = pw * (logf(pw + 1e-6f) - logf(qn + 1e-6f));
  float kl = wredsum(kle);
  if (lane == 0){
    out[1 + ray] = depth;
    out[1 + R_RAYS + ray*3 + 0] = c0;
    out[1 + R_RAYS + ray*3 + 1] = c1;
    out[1 + R_RAYS + ray*3 + 2] = c2;
    float d2c = fminf(fminf(fabsf(mg[0]-depth), fabsf(mg[1]-depth)),
                      fminf(fabsf(mg[2]-depth), fabsf(mg[3]-depth)));
    float s0 = src_col[ray*3], s1 = src_col[ray*3+1], s2 = src_col[ray*3+2];
    float closs = fabsf(s0-c0) + fabsf(s1-c1) + fabsf(s2-c2);
    float cx = cam_dir[ray*3]*depth, cy = cam_dir[ray*3+1]*depth, cz = cam_dir[ray*3+2]*depth;
    float t0 = s2t[0]*cx + s2t[1]*cy + s2t[2]*cz + s2t[3];
    float t1 = s2t[4]*cx + s2t[5]*cy + s2t[6]*cz + s2t[7];
    float t2 = s2t[8]*cx + s2t[9]*cy + s2t[10]*cz + s2t[11];
    float pr0 = camK[0]*t0 + camK[1]*t1 + camK[2]*t2;
    float pr1 = camK[3]*t0 + camK[4]*t1 + camK[5]*t2;
    float pr2 = camK[6]*t0 + camK[7]*t1 + camK[8]*t2;
    float u = pr0/(pr2 + 1e-6f), vv = pr1/(pr2 + 1e-6f);
    float tc[3]; sample_img3(tgt_img, u, vv, tc);
    float mask = (depth < 30.f) ? 1.f : 0.f;
    float adm = (fabsf(tc[0]-s0) + fabsf(tc[1]-s1) + fabsf(tc[2]-s2)) * (1.f/3.f) * mask;
    atomicAdd(&acc[0], kl);
    atomicAdd(&acc[1], d2c);
    atomicAdd(&acc[2], closs);
    atomicAdd(&acc[3], adm);
    atomicAdd(&acc[4], mask);
  }
}

__global__ void k_final(const float* __restrict__ acc, float* __restrict__ out){
  float total = acc[0] * (1.f/4096.f)
              + 0.01f * acc[1] * (1.f/4096.f)
              + acc[2] * (1.f/(3.f*4096.f))
              + acc[3] / (acc[4] + 1e-6f);
  out[0] = total;
}

// shared launch body for a given voxel precision
template<typename VT>
void launch_all(const float* bev, const float* src, const float* tgt,
                const float* camK, const float* s2i, const float* s2t,
                const float* pix, const float* const* m1p, const float* const* m2p,
                char* ws, float* outb, hipStream_t stream){
  size_t off = 0;
  float* accv     = (float*)(ws + off);     off += 256;
  VT*    vox      = (VT*)(ws + off);        off += (size_t)NVOX * 128 * sizeof(VT);
  float* ray_dir  = (float*)(ws + off);     off += (size_t)R_RAYS * 3 * 4;
  float* ray_vd   = (float*)(ws + off);     off += (size_t)R_RAYS * 3 * 4;
  float* cam_dirA = (float*)(ws + off);     off += (size_t)R_RAYS * 3 * 4;
  float* src_colA = (float*)(ws + off);     off += (size_t)R_RAYS * 3 * 4;
  float* g_means  = (float*)(ws + off);     off += (size_t)R_RAYS * 4 * 4;
  float* g_stds   = (float*)(ws + off);     off += (size_t)R_RAYS * 4 * 4;
  float* out_g    = (float*)(ws + off);     off += (size_t)R_RAYS * 4 * 2 * 4;
  float* d_allv   = (float*)(ws + off);     off += (size_t)R_RAYS * 64 * 4;
  float* out_main = (float*)(ws + off);     off += (size_t)R_RAYS * 64 * 4 * 4;

  hipMemsetAsync(accv, 0, 256, stream);
  k_transpose<VT><<<(NVOX + 255)/256, 256, 0, stream>>>(bev, vox);
  k_raysetup<<<R_RAYS/256, 256, 0, stream>>>(pix, camK, s2i, src, ray_dir, ray_vd, cam_dirA, src_colA);
  k_mlp<2,0,VT><<<(R_RAYS*4)/32, 256, 0, stream>>>(vox, ray_dir, ray_vd, s2i, d_allv,
      m2p[0], m2p[1], m2p[2], m2p[3], m2p[4], m2p[5], m2p[6], m2p[7], m2p[8], m2p[9], out_g);
  k_dall<<<R_RAYS/4, 256, 0, stream>>>(out_g, d_allv, g_means, g_stds);
  k_mlp<4,1,VT><<<(R_RAYS*64)/32, 256, 0, stream>>>(vox, ray_dir, ray_vd, s2i, d_allv,
      m1p[0], m1p[1], m1p[2], m1p[3], m1p[4], m1p[5], m1p[6], m1p[7], m1p[8], m1p[9], out_main);
  k_render<<<R_RAYS/4, 256, 0, stream>>>(out_main, d_allv, g_means, g_stds, src_colA, cam_dirA,
                                         s2t, camK, tgt, accv, outb);
  k_final<<<1, 1, 0, stream>>>(accv, outb);
}

} // anonymous namespace

extern "C" void kernel_launch(void* const* d_in, const int* in_sizes, int n_in,
                              void* d_out, int out_size, void* d_ws, size_t ws_size,
                              hipStream_t stream){
  (void)in_sizes; (void)n_in; (void)out_size;
  const float* bev  = (const float*)d_in[0];
  const float* src  = (const float*)d_in[1];
  const float* tgt  = (const float*)d_in[2];
  const float* camK = (const float*)d_in[3];
  const float* s2i  = (const float*)d_in[4];
  const float* s2t  = (const float*)d_in[5];
  const float* pix  = (const float*)d_in[6];
  const float* m1p[10]; for (int i = 0; i < 10; ++i) m1p[i] = (const float*)d_in[7 + i];
  const float* m2p[10]; for (int i = 0; i < 10; ++i) m2p[i] = (const float*)d_in[17 + i];

  // f32 voxel grid needs ~169.6 MB of workspace; fall back to fp16 (~87.7 MB)
  // if the workspace is smaller. ws_size is constant per session -> the branch
  // resolves identically on every call (graph-capture safe).
  const size_t need_f32 = 256 + (size_t)NVOX*128*4 + 6u*1024*1024;
  if (ws_size >= need_f32)
    launch_all<float>(bev, src, tgt, camK, s2i, s2t, pix, m1p, m2p, (char*)d_ws, (float*)d_out, stream);
  else
    launch_all<_Float16>(bev, src, tgt, camK, s2i, s2t, pix, m1p, m2p, (char*)d_ws, (float*)d_out, stream);
}